// Round 1
// baseline (832.539 us; speedup 1.0000x reference)
//
#include <hip/hip_runtime.h>
#include <stdint.h>
#include <stddef.h>

#define B_N   2048
#define T_SEQ 200
#define H_DIM 128

typedef __attribute__((ext_vector_type(8))) short short8;
typedef __attribute__((ext_vector_type(4))) float floatx4;

__device__ __forceinline__ unsigned short f2bf(float f) {
  union { float f; unsigned u; } v; v.f = f;
  unsigned u = v.u;
  u += 0x7FFFu + ((u >> 16) & 1u);   // round-to-nearest-even
  return (unsigned short)(u >> 16);
}

__device__ __forceinline__ float sigm(float x) {
  return 1.0f / (1.0f + __expf(-x));
}
__device__ __forceinline__ float tanh_f(float x) {
  x = fminf(15.0f, fmaxf(-15.0f, x));
  float e = __expf(-2.0f * x);
  return (1.0f - e) / (1.0f + e);
}

__device__ __forceinline__ floatx4 mfma16(short8 a, short8 b, floatx4 c) {
  return __builtin_amdgcn_mfma_f32_16x16x32_bf16(a, b, c, 0, 0, 0);
}

__device__ __forceinline__ short8 pack8(const float* p) {
  short8 r;
#pragma unroll
  for (int j = 0; j < 8; ++j) r[j] = (short)f2bf(p[j]);
  return r;
}

// ---------------------------------------------------------------------------
// Attention kernel: att[b,t] = Wd . sigmoid(W1 . sigmoid(W0 . [q,k,q-k,q*k] + b0) + b1) + bd
// Fold: pre0[o] = c[b,o] + sum_i k_i*u2[o,i] + (q_i*k_i)*u3[o,i]   (K=256 instead of 512)
// Block: one b, 64 t's. Layer0 via bf16 MFMA (M=16 t, N=64 o, K=256).
// ---------------------------------------------------------------------------
__global__ __launch_bounds__(256) void att_kernel(
    const float* __restrict__ query, const float* __restrict__ keys,
    const float* __restrict__ W0, const float* __restrict__ b0,
    const float* __restrict__ W1, const float* __restrict__ b1,
    const float* __restrict__ Wd, const float* __restrict__ bd,
    const int* __restrict__ klen, float* __restrict__ att)
{
  const int b   = blockIdx.y;
  const int tt0 = blockIdx.x * 64;
  const int tid = threadIdx.x;
  const int lane = tid & 63, wv = tid >> 6;

  __shared__ float qs[H_DIM];
  __shared__ float cs[64];
  __shared__ float part[4][64];
  __shared__ unsigned short A[64][264];     // [t][k] bf16, K=256 + pad8
  __shared__ float a0s[64][68];             // layer0 activations, pad
  __shared__ float a1s[64][20];             // layer1 activations, pad

  const int len = klen[b];
  if (tt0 >= len) {                         // whole tile masked -> zeros
    for (int t2 = tid; t2 < 64; t2 += 256) {
      int tg = tt0 + t2;
      if (tg < T_SEQ) att[(size_t)b * T_SEQ + tg] = 0.0f;
    }
    return;
  }

  if (tid < H_DIM) qs[tid] = query[(size_t)b * H_DIM + tid];
  __syncthreads();

  // c[o] partials: c = b0 + q . (W0[:, :128] + W0[:, 256:384])
  {
    int o = tid & 63, p = tid >> 6;
    const float* w = W0 + o * 512 + p * 32;
    float s = 0.0f;
#pragma unroll 8
    for (int i = 0; i < 32; ++i) s += qs[p * 32 + i] * (w[i] + w[256 + i]);
    part[p][o] = s;
  }
  // Stage A = [k | q*k] in bf16
  {
    int tl = tid >> 2, q4 = tid & 3;
    int tg = tt0 + tl;
    bool v = (tg < T_SEQ);
    const float* krow = keys + ((size_t)b * T_SEQ + (v ? tg : 0)) * H_DIM + q4 * 32;
#pragma unroll
    for (int i = 0; i < 32; i += 4) {
      float4 kv = v ? *(const float4*)(krow + i) : make_float4(0.f, 0.f, 0.f, 0.f);
      int col = q4 * 32 + i;
      A[tl][col + 0] = f2bf(kv.x);
      A[tl][col + 1] = f2bf(kv.y);
      A[tl][col + 2] = f2bf(kv.z);
      A[tl][col + 3] = f2bf(kv.w);
      A[tl][128 + col + 0] = f2bf(kv.x * qs[col + 0]);
      A[tl][128 + col + 1] = f2bf(kv.y * qs[col + 1]);
      A[tl][128 + col + 2] = f2bf(kv.z * qs[col + 2]);
      A[tl][128 + col + 3] = f2bf(kv.w * qs[col + 3]);
    }
  }
  __syncthreads();
  if (tid < 64) cs[tid] = b0[tid] + part[0][tid] + part[1][tid] + part[2][tid] + part[3][tid];
  __syncthreads();

  // B fragments: B[k][o] = u2[o][k] (k<128) | u3[o][k-128]
  short8 bf[8];
  {
    int o = wv * 16 + (lane & 15);
    int k0 = (lane >> 4) * 8;
    const float* w = W0 + o * 512;
#pragma unroll
    for (int kc = 0; kc < 8; ++kc) {
      int kk = kc * 32 + k0;
      float f[8];
      if (kk < 128) {
#pragma unroll
        for (int j = 0; j < 8; ++j) f[j] = w[128 + kk + j] - w[256 + kk + j];
      } else {
#pragma unroll
        for (int j = 0; j < 8; ++j) f[j] = w[384 + (kk - 128) + j];
      }
      short8 t;
#pragma unroll
      for (int j = 0; j < 8; ++j) t[j] = (short)f2bf(f[j]);
      bf[kc] = t;
    }
  }
  float co = cs[wv * 16 + (lane & 15)];

  // layer0 MFMA: wave wv owns o-tile wv
#pragma unroll
  for (int tt = 0; tt < 4; ++tt) {
    floatx4 acc = {0.f, 0.f, 0.f, 0.f};
    int row = tt * 16 + (lane & 15);
    int kb = (lane >> 4) * 8;
#pragma unroll
    for (int kc = 0; kc < 8; ++kc) {
      short8 af = *(const short8*)&A[row][kc * 32 + kb];
      acc = mfma16(af, bf[kc], acc);
    }
#pragma unroll
    for (int r = 0; r < 4; ++r) {
      int trow = tt * 16 + (lane >> 4) * 4 + r;
      a0s[trow][wv * 16 + (lane & 15)] = sigm(acc[r] + co);
    }
  }
  __syncthreads();

  // layer1 (fp32 vector): 64 t-lanes x 4 o-groups
  {
    int t = tid & 63, og = tid >> 6;
    float s[4] = {0.f, 0.f, 0.f, 0.f};
#pragma unroll 4
    for (int i = 0; i < 64; i += 4) {
      float4 av = *(const float4*)&a0s[t][i];
#pragma unroll
      for (int oo = 0; oo < 4; ++oo) {
        const float* w1 = W1 + (og * 4 + oo) * 64 + i;
        s[oo] += av.x * w1[0] + av.y * w1[1] + av.z * w1[2] + av.w * w1[3];
      }
    }
#pragma unroll
    for (int oo = 0; oo < 4; ++oo) a1s[t][og * 4 + oo] = sigm(s[oo] + b1[og * 4 + oo]);
  }
  __syncthreads();

  if (tid < 64) {
    int tg = tt0 + tid;
    if (tg < T_SEQ) {
      float s = bd[0];
#pragma unroll
      for (int i = 0; i < 16; ++i) s += a1s[tid][i] * Wd[i];
      att[(size_t)b * T_SEQ + tg] = (tg < len) ? s : 0.0f;
    }
  }
}

// ---------------------------------------------------------------------------
// Fused AUGRU scan. 128 blocks x 16 batch rows x 512 threads (8 waves).
// Per step: gh = h@Whh^T, gi = k_t@Wih^T via bf16 MFMA (weights in register
// B-frags), gates fully in-register (lane owns same (m,j) in D-layout as the
// h elements it updates). h fp32 in registers; bf16 copy in LDS for A-frags.
// ---------------------------------------------------------------------------
__global__ __launch_bounds__(512, 2) void scan_kernel(
    const float* __restrict__ keys, const float* __restrict__ Wih,
    const float* __restrict__ Whh, const float* __restrict__ bih,
    const float* __restrict__ bhh, const int* __restrict__ klen,
    const float* __restrict__ att, float* __restrict__ out)
{
  const int bid = blockIdx.x;
  const int r0  = bid * 16;
  const int tid = threadIdx.x;
  const int lane = tid & 63, wv = tid >> 6;     // wv 0..7

  __shared__ unsigned short hbf[16][136];       // bf16 h, pad 8
  __shared__ unsigned short kbf[2][16][136];    // bf16 k_t double buffer
  __shared__ float att_s[T_SEQ][16];
  __shared__ float brz[256];                    // bih+bhh for r,z sections
  __shared__ float bin_s[128];
  __shared__ float bhn_s[128];
  __shared__ int   len_s[16];

  // ---- init ----
  if (tid < 16) len_s[tid] = klen[r0 + tid];
  for (int i = tid; i < 256; i += 512) brz[i] = bih[i] + bhh[i];
  for (int i = tid; i < 128; i += 512) { bin_s[i] = bih[256 + i]; bhn_s[i] = bhh[256 + i]; }
  for (int i = tid; i < 16 * 136; i += 512) ((unsigned short*)hbf)[i] = 0;
  for (int i = tid; i < T_SEQ * 16; i += 512) {
    int t = i >> 4, m = i & 15;
    att_s[t][m] = att[(size_t)(r0 + m) * T_SEQ + t];
  }
  {  // stage k_0
    int m = tid >> 5, j = (tid & 31) * 4;
    float4 kv = *(const float4*)(keys + ((size_t)(r0 + m) * T_SEQ + 0) * H_DIM + j);
    unsigned u0 = (unsigned)f2bf(kv.x) | ((unsigned)f2bf(kv.y) << 16);
    unsigned u1 = (unsigned)f2bf(kv.z) | ((unsigned)f2bf(kv.w) << 16);
    *(unsigned*)&kbf[0][m][j]     = u0;
    *(unsigned*)&kbf[0][m][j + 2] = u1;
  }

  // ---- weight fragments in registers: B[k][n] = W[n][k], bf16 ----
  short8 whf[3][4], wif[3][4];
  const int ocol = wv * 16 + (lane & 15);       // column 0..127 within section
  const int kb = (lane >> 4) * 8;
#pragma unroll
  for (int g = 0; g < 3; ++g) {
    int row = g * 128 + ocol;
#pragma unroll
    for (int kc = 0; kc < 4; ++kc) {
      int kk = kc * 32 + kb;
      whf[g][kc] = pack8(Whh + (size_t)row * H_DIM + kk);
      wif[g][kc] = pack8(Wih + (size_t)row * H_DIM + kk);
    }
  }

  __syncthreads();

  int tmax = 0;
#pragma unroll
  for (int m = 0; m < 16; ++m) tmax = max(tmax, len_s[m]);

  const float br_  = brz[ocol];
  const float bz_  = brz[128 + ocol];
  const float bin_ = bin_s[ocol];
  const float bhn_ = bhn_s[ocol];
  int   mrow[4], lenr[4];
  float hreg[4];
#pragma unroll
  for (int r = 0; r < 4; ++r) {
    mrow[r] = (lane >> 4) * 4 + r;
    lenr[r] = len_s[mrow[r]];
    hreg[r] = 0.0f;
  }

  const int pm = tid >> 5, pj = (tid & 31) * 4;
  const int arow = lane & 15;

  for (int t = 0; t < tmax; ++t) {
    const int buf = t & 1;
    // prefetch k_{t+1}
    float4 kv;
    const bool pf = (t + 1 < tmax);
    if (pf) kv = *(const float4*)(keys + ((size_t)(r0 + pm) * T_SEQ + (t + 1)) * H_DIM + pj);

    floatx4 agh[3], agi[3];
#pragma unroll
    for (int g = 0; g < 3; ++g) { agh[g] = (floatx4){0.f,0.f,0.f,0.f}; agi[g] = (floatx4){0.f,0.f,0.f,0.f}; }

#pragma unroll
    for (int kc = 0; kc < 4; ++kc) {
      short8 ah = *(const short8*)&hbf[arow][kc * 32 + kb];
      short8 ak = *(const short8*)&kbf[buf][arow][kc * 32 + kb];
#pragma unroll
      for (int g = 0; g < 3; ++g) agh[g] = mfma16(ah, whf[g][kc], agh[g]);
#pragma unroll
      for (int g = 0; g < 3; ++g) agi[g] = mfma16(ak, wif[g][kc], agi[g]);
    }
    __syncthreads();   // all LDS reads of hbf/kbf[buf] complete

    if (pf) {
      unsigned u0 = (unsigned)f2bf(kv.x) | ((unsigned)f2bf(kv.y) << 16);
      unsigned u1 = (unsigned)f2bf(kv.z) | ((unsigned)f2bf(kv.w) << 16);
      *(unsigned*)&kbf[buf ^ 1][pm][pj]     = u0;
      *(unsigned*)&kbf[buf ^ 1][pm][pj + 2] = u1;
    }

#pragma unroll
    for (int r = 0; r < 4; ++r) {
      float at = att_s[t][mrow[r]];
      float rr = sigm(agi[0][r] + agh[0][r] + br_);
      float zz = sigm(agi[1][r] + agh[1][r] + bz_);
      float nn = tanh_f(agi[2][r] + bin_ + rr * (agh[2][r] + bhn_));
      float z2 = at * zz;
      float hn = (1.0f - z2) * hreg[r] + z2 * nn;
      if (t < lenr[r]) hreg[r] = hn;
      hbf[mrow[r]][ocol] = f2bf(hreg[r]);
    }
    __syncthreads();   // hbf/kbf writes visible before next step's reads
  }

#pragma unroll
  for (int r = 0; r < 4; ++r)
    out[(size_t)(r0 + mrow[r]) * H_DIM + ocol] = hreg[r];
}

extern "C" void kernel_launch(void* const* d_in, const int* in_sizes, int n_in,
                              void* d_out, int out_size, void* d_ws, size_t ws_size,
                              hipStream_t stream) {
  const float* query = (const float*)d_in[0];
  const float* keys  = (const float*)d_in[1];
  const float* W0    = (const float*)d_in[2];
  const float* b0    = (const float*)d_in[3];
  const float* W1    = (const float*)d_in[4];
  const float* b1    = (const float*)d_in[5];
  const float* Wd    = (const float*)d_in[6];
  const float* bd    = (const float*)d_in[7];
  const float* Wih   = (const float*)d_in[8];
  const float* Whh   = (const float*)d_in[9];
  const float* bih   = (const float*)d_in[10];
  const float* bhh   = (const float*)d_in[11];
  const int*   klen  = (const int*)d_in[12];
  float* att = (float*)d_ws;           // [B, T] f32 = 1.64 MB
  float* out = (float*)d_out;

  hipLaunchKernelGGL(att_kernel, dim3(4, B_N), dim3(256), 0, stream,
                     query, keys, W0, b0, W1, b1, Wd, bd, klen, att);
  hipLaunchKernelGGL(scan_kernel, dim3(B_N / 16), dim3(512), 0, stream,
                     keys, Wih, Whh, bih, bhh, klen, att, out);
}

// Round 2
// 630.997 us; speedup vs baseline: 1.3194x; 1.3194x over previous
//
#include <hip/hip_runtime.h>
#include <stdint.h>
#include <stddef.h>

#define B_N   2048
#define T_SEQ 200
#define H_DIM 128

typedef __attribute__((ext_vector_type(8))) short short8;
typedef __attribute__((ext_vector_type(4))) float floatx4;

// ws layout (bytes) — total 1,411,072 <= 1,638,400 proven safe in R1
#define OFF_ATT 0u         // ushort[B][T]        819200
#define OFF_C   819200u    // float [B][64]       524288
#define OFF_U1  1343488u   // float [128][64]      32768
#define OFF_FR  1376256u   // short8[4][8][64]     32768
#define OFF_W1F 1409024u   // short8[2][64]         2048

__device__ __forceinline__ unsigned rnd_bf(float f) {
  union { float f; unsigned u; } v; v.f = f;
  return v.u + 0x7FFFu + ((v.u >> 16) & 1u);
}
__device__ __forceinline__ unsigned short f2bf(float f) {
  return (unsigned short)(rnd_bf(f) >> 16);
}
// pack two floats -> dword of 2 bf16 (lo in low16) via v_perm_b32
__device__ __forceinline__ unsigned pack2bf(float lo, float hi) {
  return __builtin_amdgcn_perm(rnd_bf(hi), rnd_bf(lo), 0x07060302u);
}
__device__ __forceinline__ float bf2f(unsigned short u) {
  union { unsigned u; float f; } v; v.u = ((unsigned)u) << 16; return v.f;
}

#define LOG2E 1.4426950408889634f
__device__ __forceinline__ float fsig(float x) {        // 1/(1+2^(-x*log2e))
  return 1.0f / (1.0f + __builtin_amdgcn_exp2f(-LOG2E * x));
}
__device__ __forceinline__ float ftanh(float x) {       // 2/(1+2^(-2x*log2e)) - 1
  return fmaf(2.0f, 1.0f / (1.0f + __builtin_amdgcn_exp2f(-2.0f * LOG2E * x)), -1.0f);
}

__device__ __forceinline__ floatx4 mfma16(short8 a, short8 b, floatx4 c) {
  return __builtin_amdgcn_mfma_f32_16x16x32_bf16(a, b, c, 0, 0, 0);
}
__device__ __forceinline__ short8 pack8(const float* p) {
  short8 r;
#pragma unroll
  for (int j = 0; j < 8; ++j) r[j] = (short)f2bf(p[j]);
  return r;
}

// ---------------------------------------------------------------------------
// prep: fold W0 into u1 (fp32, for c-GEMM) and bf16 MFMA B-fragments for
// layer0 (u2|u3) and layer1 (W1^T). One block, runs once per launch.
// ---------------------------------------------------------------------------
__global__ __launch_bounds__(256) void prep_kernel(
    const float* __restrict__ W0, const float* __restrict__ W1,
    float* __restrict__ u1_ws, short8* __restrict__ fr_ws,
    short8* __restrict__ w1f_ws)
{
  const int tid = threadIdx.x;
  for (int i = tid; i < 128 * 64; i += 256) {
    int k = i >> 6, o = i & 63;
    u1_ws[i] = W0[o * 512 + k] + W0[o * 512 + 256 + k];
  }
  for (int f = tid; f < 4 * 8 * 64; f += 256) {
    int ln = f & 63, kc = (f >> 6) & 7, tt = f >> 9;
    int o = tt * 16 + (ln & 15);
    int k0 = kc * 32 + ((ln >> 4) * 8);
    short8 v;
#pragma unroll
    for (int j = 0; j < 8; ++j) {
      int ks = k0 + j;
      float x = (ks < 128) ? (W0[o * 512 + 128 + ks] - W0[o * 512 + 256 + ks])
                           : W0[o * 512 + 384 + (ks - 128)];
      v[j] = (short)f2bf(x);
    }
    fr_ws[f] = v;
  }
  for (int f = tid; f < 2 * 64; f += 256) {
    int ln = f & 63, kc = f >> 6;
    int n = ln & 15, k0 = kc * 32 + ((ln >> 4) * 8);
    short8 v;
#pragma unroll
    for (int j = 0; j < 8; ++j) v[j] = (short)f2bf(W1[n * 64 + k0 + j]);
    w1f_ws[f] = v;
  }
}

// ---------------------------------------------------------------------------
// c_kernel: c[b][o] = b0[o] + sum_k q[b][k] * u1[k][o].  16 b per block.
// ---------------------------------------------------------------------------
__global__ __launch_bounds__(256) void c_kernel(
    const float* __restrict__ query, const float* __restrict__ u1_ws,
    const float* __restrict__ b0, float* __restrict__ c_ws)
{
  const int blk = blockIdx.x, tid = threadIdx.x;
  __shared__ float qs[16 * 128];
  for (int i = tid; i < 512; i += 256)
    *(float4*)&qs[i * 4] = *(const float4*)(query + (size_t)blk * 2048 + i * 4);
  __syncthreads();
  const int o = tid & 63, bb = tid >> 6;
  float a0 = b0[o], a1 = a0, a2 = a0, a3 = a0;
  const float* qr = qs + bb * 512;
#pragma unroll 4
  for (int k = 0; k < 128; ++k) {
    float w = u1_ws[k * 64 + o];
    a0 = fmaf(qr[k], w, a0);
    a1 = fmaf(qr[128 + k], w, a1);
    a2 = fmaf(qr[256 + k], w, a2);
    a3 = fmaf(qr[384 + k], w, a3);
  }
  const int b = blk * 16 + bb * 4;
  c_ws[(b + 0) * 64 + o] = a0;
  c_ws[(b + 1) * 64 + o] = a1;
  c_ws[(b + 2) * 64 + o] = a2;
  c_ws[(b + 3) * 64 + o] = a3;
}

// ---------------------------------------------------------------------------
// att: layer0 bf16 MFMA (frags from ws), layer1 bf16 MFMA, layer2 tiny dot.
// Output bf16 scores.
// ---------------------------------------------------------------------------
__global__ __launch_bounds__(256) void att_kernel(
    const float* __restrict__ query, const float* __restrict__ keys,
    const float* __restrict__ c_ws, const short8* __restrict__ fr_ws,
    const short8* __restrict__ w1f_ws, const float* __restrict__ b1,
    const float* __restrict__ Wd, const float* __restrict__ bd,
    const int* __restrict__ klen, unsigned short* __restrict__ attb)
{
  const int b   = blockIdx.y;
  const int tt0 = blockIdx.x * 64;
  const int tid = threadIdx.x;
  const int lane = tid & 63, wv = tid >> 6;
  const int kb = (lane >> 4) * 8;

  __shared__ float qs[H_DIM];
  __shared__ unsigned short A[64][264];     // [t][k] bf16, K=256, 16B-odd stride
  __shared__ unsigned short a0b[64][72];    // layer0 activations bf16
  __shared__ float a1s[64][20];

  const int len = klen[b];
  if (tt0 >= len) {
    for (int t2 = tid; t2 < 64; t2 += 256) {
      int tg = tt0 + t2;
      if (tg < T_SEQ) attb[(size_t)b * T_SEQ + tg] = 0;
    }
    return;
  }

  if (tid < H_DIM) qs[tid] = query[(size_t)b * H_DIM + tid];
  __syncthreads();

  {  // stage A = [k | q*k] bf16
    int tl = tid >> 2, q4 = tid & 3;
    int tg = tt0 + tl;
    bool v = (tg < T_SEQ);
    const float* krow = keys + ((size_t)b * T_SEQ + (v ? tg : 0)) * H_DIM + q4 * 32;
#pragma unroll
    for (int i = 0; i < 32; i += 4) {
      float4 kv = v ? *(const float4*)(krow + i) : make_float4(0.f, 0.f, 0.f, 0.f);
      int col = q4 * 32 + i;
      *(unsigned*)&A[tl][col]     = pack2bf(kv.x, kv.y);
      *(unsigned*)&A[tl][col + 2] = pack2bf(kv.z, kv.w);
      *(unsigned*)&A[tl][128 + col]     = pack2bf(kv.x * qs[col + 0], kv.y * qs[col + 1]);
      *(unsigned*)&A[tl][128 + col + 2] = pack2bf(kv.z * qs[col + 2], kv.w * qs[col + 3]);
    }
  }
  // B-fragments for this wave's o-tile (prebuilt in ws)
  short8 bf[8];
  {
    const short8* frp = fr_ws + (size_t)wv * 8 * 64;
#pragma unroll
    for (int kc = 0; kc < 8; ++kc) bf[kc] = frp[kc * 64 + lane];
  }
  const float co = c_ws[(size_t)b * 64 + wv * 16 + (lane & 15)];
  __syncthreads();

  // layer0 MFMA
#pragma unroll
  for (int tt = 0; tt < 4; ++tt) {
    floatx4 acc = {co, co, co, co};
    int row = tt * 16 + (lane & 15);
#pragma unroll
    for (int kc = 0; kc < 8; ++kc)
      acc = mfma16(*(const short8*)&A[row][kc * 32 + kb], bf[kc], acc);
#pragma unroll
    for (int r = 0; r < 4; ++r)
      a0b[tt * 16 + (lane >> 4) * 4 + r][wv * 16 + (lane & 15)] = f2bf(fsig(acc[r]));
  }
  __syncthreads();

  // layer1 MFMA: wave wv owns t-rows wv*16..+15, 16 outputs
  {
    short8 w1f0 = w1f_ws[lane], w1f1 = w1f_ws[64 + lane];
    float b1v = b1[lane & 15];
    floatx4 acc1 = {b1v, b1v, b1v, b1v};
    int r2 = wv * 16 + (lane & 15);
    acc1 = mfma16(*(const short8*)&a0b[r2][kb],      w1f0, acc1);
    acc1 = mfma16(*(const short8*)&a0b[r2][32 + kb], w1f1, acc1);
#pragma unroll
    for (int r = 0; r < 4; ++r)
      a1s[wv * 16 + (lane >> 4) * 4 + r][lane & 15] = fsig(acc1[r]);
  }
  __syncthreads();

  if (tid < 64) {
    int tg = tt0 + tid;
    if (tg < T_SEQ) {
      float s = bd[0];
#pragma unroll
      for (int i = 0; i < 16; ++i) s += a1s[tid][i] * Wd[i];
      attb[(size_t)b * T_SEQ + tg] = (tg < len) ? f2bf(s) : (unsigned short)0;
    }
  }
}

// ---------------------------------------------------------------------------
// AUGRU scan: 128 blocks x 16 rows x 512 thr. ONE barrier/step (lgkm-only),
// double-buffered h AND k in LDS, k prefetched TWO steps ahead (vmcnt stays
// in flight across the barrier). 4 accumulators (gi folded into r/z).
// ---------------------------------------------------------------------------
__global__ __launch_bounds__(512, 2) void scan_kernel(
    const float* __restrict__ keys, const float* __restrict__ Wih,
    const float* __restrict__ Whh, const float* __restrict__ bih,
    const float* __restrict__ bhh, const int* __restrict__ klen,
    const unsigned short* __restrict__ attb, float* __restrict__ out)
{
  const int r0 = blockIdx.x * 16;
  const int tid = threadIdx.x;
  const int lane = tid & 63, wv = tid >> 6;

  __shared__ unsigned short hbf[2][16][136];
  __shared__ unsigned short kbf[2][16][136];
  __shared__ float att_s[T_SEQ][16];
  __shared__ int len_s[16];

  if (tid < 16) len_s[tid] = klen[r0 + tid];
  for (int i = tid; i < 16 * 136; i += 512) ((unsigned short*)hbf[0])[i] = 0;
  for (int i = tid; i < T_SEQ * 16; i += 512) {
    int t = i >> 4, m = i & 15;
    att_s[t][m] = bf2f(attb[(size_t)(r0 + m) * T_SEQ + t]);
  }
  const int pm = tid >> 5, pj = (tid & 31) * 4;
  const float* kbase = keys + ((size_t)(r0 + pm) * T_SEQ) * H_DIM + pj;
  {  // k_0 -> kbf[0]
    float4 kv = *(const float4*)kbase;
    uint2 p; p.x = pack2bf(kv.x, kv.y); p.y = pack2bf(kv.z, kv.w);
    *(uint2*)&kbf[0][pm][pj] = p;
  }
  float4 kv_next = *(const float4*)(kbase + H_DIM);  // k_1 (T>=2 always)

  // weight fragments (B): lane holds W[g*128+ocol][k-slice]
  short8 whf[3][4], wif[3][4];
  const int ocol = wv * 16 + (lane & 15);
  const int kb = (lane >> 4) * 8;
#pragma unroll
  for (int g = 0; g < 3; ++g) {
    int row = g * 128 + ocol;
#pragma unroll
    for (int kc = 0; kc < 4; ++kc) {
      int kk = kc * 32 + kb;
      whf[g][kc] = pack8(Whh + (size_t)row * H_DIM + kk);
      wif[g][kc] = pack8(Wih + (size_t)row * H_DIM + kk);
    }
  }
  const float br_  = bih[ocol] + bhh[ocol];
  const float bz_  = bih[128 + ocol] + bhh[128 + ocol];
  const float bin_ = bih[256 + ocol];
  const float bhn_ = bhh[256 + ocol];

  __syncthreads();

  int tmax = 0;
#pragma unroll
  for (int m = 0; m < 16; ++m) tmax = max(tmax, len_s[m]);
  const int mrow0 = (lane >> 4) * 4;
  int lenr[4];
  float hreg[4];
#pragma unroll
  for (int r = 0; r < 4; ++r) { lenr[r] = len_s[mrow0 + r]; hreg[r] = 0.0f; }
  const int arow = lane & 15;

  for (int t = 0; t < tmax; ++t) {
    const int buf = t & 1, nbuf = buf ^ 1;
    int tf = t + 2; if (tf > T_SEQ - 1) tf = T_SEQ - 1;
    float4 kv_fut = *(const float4*)(kbase + (size_t)tf * H_DIM);  // 2-ahead

    short8 ah0 = *(const short8*)&hbf[buf][arow][kb];
    short8 ah1 = *(const short8*)&hbf[buf][arow][32 + kb];
    short8 ah2 = *(const short8*)&hbf[buf][arow][64 + kb];
    short8 ah3 = *(const short8*)&hbf[buf][arow][96 + kb];
    short8 ak0 = *(const short8*)&kbf[buf][arow][kb];
    short8 ak1 = *(const short8*)&kbf[buf][arow][32 + kb];
    short8 ak2 = *(const short8*)&kbf[buf][arow][64 + kb];
    short8 ak3 = *(const short8*)&kbf[buf][arow][96 + kb];

    floatx4 acc_r = {br_, br_, br_, br_};
    floatx4 acc_z = {bz_, bz_, bz_, bz_};
    floatx4 ahn   = {bhn_, bhn_, bhn_, bhn_};
    floatx4 ain   = {bin_, bin_, bin_, bin_};

    acc_r = mfma16(ah0, whf[0][0], acc_r); acc_r = mfma16(ak0, wif[0][0], acc_r);
    acc_z = mfma16(ah0, whf[1][0], acc_z); acc_z = mfma16(ak0, wif[1][0], acc_z);
    ahn   = mfma16(ah0, whf[2][0], ahn);   ain   = mfma16(ak0, wif[2][0], ain);
    acc_r = mfma16(ah1, whf[0][1], acc_r); acc_r = mfma16(ak1, wif[0][1], acc_r);
    acc_z = mfma16(ah1, whf[1][1], acc_z); acc_z = mfma16(ak1, wif[1][1], acc_z);
    ahn   = mfma16(ah1, whf[2][1], ahn);   ain   = mfma16(ak1, wif[2][1], ain);
    acc_r = mfma16(ah2, whf[0][2], acc_r); acc_r = mfma16(ak2, wif[0][2], acc_r);
    acc_z = mfma16(ah2, whf[1][2], acc_z); acc_z = mfma16(ak2, wif[1][2], acc_z);
    ahn   = mfma16(ah2, whf[2][2], ahn);   ain   = mfma16(ak2, wif[2][2], ain);
    acc_r = mfma16(ah3, whf[0][3], acc_r); acc_r = mfma16(ak3, wif[0][3], acc_r);
    acc_z = mfma16(ah3, whf[1][3], acc_z); acc_z = mfma16(ak3, wif[1][3], acc_z);
    ahn   = mfma16(ah3, whf[2][3], ahn);   ain   = mfma16(ak3, wif[2][3], ain);

#pragma unroll
    for (int r = 0; r < 4; ++r) {
      float at = att_s[t][mrow0 + r];
      float rr = fsig(acc_r[r]);
      float zz = fsig(acc_z[r]);
      float nn = ftanh(ain[r] + rr * ahn[r]);
      float z2 = at * zz;
      float hn = fmaf(z2, nn - hreg[r], hreg[r]);
      hreg[r] = (t < lenr[r]) ? hn : hreg[r];
      hbf[nbuf][mrow0 + r][ocol] = f2bf(hreg[r]);
    }
    {  // stage k_{t+1} (loaded last step) into next buffer
      uint2 p; p.x = pack2bf(kv_next.x, kv_next.y); p.y = pack2bf(kv_next.z, kv_next.w);
      *(uint2*)&kbf[nbuf][pm][pj] = p;
    }
    kv_next = kv_fut;
    // lgkm-only barrier: do NOT drain vmcnt (k prefetch stays in flight)
    __asm__ volatile("s_waitcnt lgkmcnt(0)\n\ts_barrier" ::: "memory");
  }

#pragma unroll
  for (int r = 0; r < 4; ++r)
    out[(size_t)(r0 + mrow0 + r) * H_DIM + ocol] = hreg[r];
}

extern "C" void kernel_launch(void* const* d_in, const int* in_sizes, int n_in,
                              void* d_out, int out_size, void* d_ws, size_t ws_size,
                              hipStream_t stream) {
  const float* query = (const float*)d_in[0];
  const float* keys  = (const float*)d_in[1];
  const float* W0    = (const float*)d_in[2];
  const float* b0    = (const float*)d_in[3];
  const float* W1    = (const float*)d_in[4];
  const float* b1    = (const float*)d_in[5];
  const float* Wd    = (const float*)d_in[6];
  const float* bd    = (const float*)d_in[7];
  const float* Wih   = (const float*)d_in[8];
  const float* Whh   = (const float*)d_in[9];
  const float* bih   = (const float*)d_in[10];
  const float* bhh   = (const float*)d_in[11];
  const int*   klen  = (const int*)d_in[12];

  char* ws = (char*)d_ws;
  unsigned short* att_bf = (unsigned short*)(ws + OFF_ATT);
  float*  c_ws  = (float*)(ws + OFF_C);
  float*  u1_ws = (float*)(ws + OFF_U1);
  short8* fr_ws = (short8*)(ws + OFF_FR);
  short8* w1f_ws = (short8*)(ws + OFF_W1F);
  float* out = (float*)d_out;

  hipLaunchKernelGGL(prep_kernel, dim3(1), dim3(256), 0, stream, W0, W1, u1_ws, fr_ws, w1f_ws);
  hipLaunchKernelGGL(c_kernel, dim3(B_N / 16), dim3(256), 0, stream, query, u1_ws, b0, c_ws);
  hipLaunchKernelGGL(att_kernel, dim3(4, B_N), dim3(256), 0, stream,
                     query, keys, c_ws, fr_ws, w1f_ws, b1, Wd, bd, klen, att_bf);
  hipLaunchKernelGGL(scan_kernel, dim3(B_N / 16), dim3(512), 0, stream,
                     keys, Wih, Whh, bih, bhh, klen, att_bf, out);
}